// Round 7
// baseline (3901.629 us; speedup 1.0000x reference)
//
#include <hip/hip_runtime.h>

#define SMP 32      // samples per block (= lanes 0-31; lane>>5 picks column-half)
#define NW 8        // waves per block (512 threads)
#define NT (NW*64)
#define SLC 8       // hidden columns per thread slice (16 slices x 8 = 128)

constexpr float DTc  = 0.02f;
constexpr float ADc  = (2.0f/3.0f)*0.02f;   // alpha*DT
constexpr float EPSc = 1e-6f;

// S (per-sample small state) field offsets, stride 151 (odd -> conflict-free)
#define FQ   0    // q (6)
#define FQD  6    // qdot (6)
#define FL   12   // 21 tril entries of L (y accumulator, init = b3L)
#define FM   33   // 36 full symmetric M
#define FU   69   // u = M qd (6)
#define FP   75   // p = L^T qd (6)
#define FR   81   // r = L^T u (6)
#define FDY  87   // dy: JVP of y along qd (21, atomic)
#define FDV  108  // dV/dq (6)
#define FGV  114  // V-grad wrt trig feats (12, atomic)
#define FGL  126  // c2-scalar grad wrt trig feats (12, atomic)
#define FC1  138  // c1 = B u + M B qd (6)
#define FKQ  144  // qddot of stage 1 (k1) (6)
#define SSTR 151

#define HS 129    // odd stride for 128-vectors

// Model fitted to rounds 0-6: __launch_bounds__ 2nd arg acts as min BLOCKS/CU.
// (1024,4)->64 waves/CU->cap 64 VGPR (r1-3); (512,2)->16 waves/CU->cap 128:
// round 0 (demand 116) fit, rounds 4-6 (demand ~150) spilled 27-44 MB/dispatch.
// Fix = demand < 128 (SLC=8 arrays) + LDS < 80 KB for 2 blocks/CU (SMP=32).

__device__ __forceinline__ float softplusf(float z) {
    return fmaxf(z, 0.0f) + __logf(1.0f + __expf(-fabsf(z)));
}
__device__ __forceinline__ float sigmoidf_(float z) {
    float t = __expf(-fabsf(z));
    float r = 1.0f / (1.0f + t);
    return z >= 0.0f ? r : t * r;
}

__global__ void prep_kernel(const float* __restrict__ W1L, const float* __restrict__ W1V,
                            float* __restrict__ ws) {
    int idx = blockIdx.x*256 + threadIdx.x;
    if (idx < 1536) {                       // W1LT[n*12+d] = W1L[d*128+n]
        int n = idx / 12, d = idx % 12;
        ws[idx] = W1L[d*128 + n];
    } else if (idx < 3072) {                // W1VT[m*12+d] = W1V[d*128+m]
        int j = idx - 1536;
        int m = j / 12, d = j % 12;
        ws[idx] = W1V[d*128 + m];
    }
}

__launch_bounds__(NT, 2)
__global__ void lnn_kernel(
    const float* __restrict__ o,   const float* __restrict__ aIn,
    const float* __restrict__ b1L, const float* __restrict__ W2L,
    const float* __restrict__ b2L, const float* __restrict__ W3L,
    const float* __restrict__ b3L,
    const float* __restrict__ b1V, const float* __restrict__ W2V,
    const float* __restrict__ b2V, const float* __restrict__ W3V,
    const float* __restrict__ W1LT, const float* __restrict__ W1VT,
    float* __restrict__ out)
{
    __shared__ float H1[SMP*HS];    // h1L = softplus(z1L), whole stage
    __shared__ float HVs[SMP*HS];   // h1V (P0-P2), then dh1 = JVP of h1L (P3-P4)
    __shared__ float G[SMP*HS];     // g2V (P1-P2), then gz2 (P4-P5)
    __shared__ float S[SMP*SSTR];   // total LDS = 49536 + 19328 = 68864 B -> 2 blocks/CU

    const int tid  = threadIdx.x;
    const int lane = tid & 63;
    const int wv   = __builtin_amdgcn_readfirstlane(tid >> 6);
    const int smp  = lane & 31;                   // sample within block
    const int hf   = lane >> 5;                   // column-half within wave
    const int gs   = blockIdx.x * SMP + smp;      // global sample of this lane
    const int c0   = wv*16 + hf*8;                // this thread's 8-column slice
    float* Sl    = &S[smp*SSTR];
    float* Hrow1 = &H1[smp*HS];
    float* HrowV = &HVs[smp*HS];
    float* HrowG = &G[smp*HS];

    constexpr int TRW[21] = {0,1,1,2,2,2,3,3,3,3,4,4,4,4,4,5,5,5,5,5,5};
    constexpr int TCW[21] = {0,0,1,0,1,2,0,1,2,3,0,1,2,3,4,0,1,2,3,4,5};

    float qd[6], tt[12];

    for (int stage = 0; stage < 2; ++stage) {
        // ---------------- P0: state load + trig + layer-1 (both nets, own slice) ----------------
        {
            float qv[6];
            if (stage == 0) {
                #pragma unroll
                for (int i = 0; i < 6; ++i) { qv[i] = o[gs*18+i]; qd[i] = o[gs*18+6+i]; }
                if (wv == 0 && hf == 0) {
                    #pragma unroll
                    for (int i = 0; i < 6; ++i) { Sl[FQ+i] = qv[i]; Sl[FQD+i] = qd[i]; }
                }
            } else {
                #pragma unroll
                for (int i = 0; i < 6; ++i) { qv[i] = Sl[FQ+i]; qd[i] = Sl[FQD+i]; }
            }
            #pragma unroll
            for (int i = 0; i < 6; ++i) { tt[2*i] = cosf(qv[i]); tt[2*i+1] = sinf(qv[i]); }
        }
        if (wv == 1 && hf == 0) {
            #pragma unroll
            for (int k = 0; k < 21; ++k) Sl[FL+k] = b3L[k];
        } else if (wv == 2 && hf == 0) {
            #pragma unroll
            for (int k = 0; k < 21; ++k) Sl[FDY+k] = 0.0f;
        } else if (wv == 3 && hf == 0) {
            #pragma unroll
            for (int d = 0; d < 12; ++d) { Sl[FGV+d] = 0.0f; Sl[FGL+d] = 0.0f; }
        }
        #pragma unroll
        for (int j = 0; j < SLC; ++j) {
            int m = c0 + j;
            const float4* wL = (const float4*)&W1LT[m*12];
            float4 la = wL[0], lb = wL[1], lc = wL[2];
            float zL = b1L[m]
                + tt[0]*la.x + tt[1]*la.y + tt[2] *la.z + tt[3] *la.w
                + tt[4]*lb.x + tt[5]*lb.y + tt[6] *lb.z + tt[7] *lb.w
                + tt[8]*lc.x + tt[9]*lc.y + tt[10]*lc.z + tt[11]*lc.w;
            Hrow1[m] = softplusf(zL);
            const float4* wV = (const float4*)&W1VT[m*12];
            float4 va = wV[0], vb = wV[1], vc = wV[2];
            float zV = b1V[m]
                + tt[0]*va.x + tt[1]*va.y + tt[2] *va.z + tt[3] *va.w
                + tt[4]*vb.x + tt[5]*vb.y + tt[6] *vb.z + tt[7] *vb.w
                + tt[8]*vc.x + tt[9]*vc.y + tt[10]*vc.z + tt[11]*vc.w;
            HrowV[m] = softplusf(zV);
        }
        __syncthreads();

        // ---------------- P1: fused layer-2 (L and V), y partial, g2V seed ----------------
        float sg2reg[SLC];   // sigmoid(z2L) own slice, kept in registers until P4
        {
            float accL[SLC], accV[SLC];
            #pragma unroll
            for (int j = 0; j < SLC; ++j) { accL[j] = b2L[c0+j]; accV[j] = b2V[c0+j]; }
            for (int m8 = 0; m8 < 128; m8 += 8) {
                float h1r[8], hvr[8];
                #pragma unroll
                for (int t = 0; t < 8; ++t) { h1r[t] = Hrow1[m8+t]; hvr[t] = HrowV[m8+t]; }
                #pragma unroll
                for (int t = 0; t < 8; ++t) {
                    const float4* w4 = (const float4*)&W2L[(m8+t)*128 + c0];
                    float4 wa = w4[0], wb = w4[1];
                    accL[0] += h1r[t]*wa.x; accL[1] += h1r[t]*wa.y;
                    accL[2] += h1r[t]*wa.z; accL[3] += h1r[t]*wa.w;
                    accL[4] += h1r[t]*wb.x; accL[5] += h1r[t]*wb.y;
                    accL[6] += h1r[t]*wb.z; accL[7] += h1r[t]*wb.w;
                    const float4* v4 = (const float4*)&W2V[(m8+t)*128 + c0];
                    float4 va = v4[0], vb = v4[1];
                    accV[0] += hvr[t]*va.x; accV[1] += hvr[t]*va.y;
                    accV[2] += hvr[t]*va.z; accV[3] += hvr[t]*va.w;
                    accV[4] += hvr[t]*vb.x; accV[5] += hvr[t]*vb.y;
                    accV[6] += hvr[t]*vb.z; accV[7] += hvr[t]*vb.w;
                }
            }
            float yp[21];
            #pragma unroll
            for (int k = 0; k < 21; ++k) yp[k] = 0.0f;
            #pragma unroll
            for (int j = 0; j < SLC; ++j) {
                int n = c0 + j;
                HrowG[n] = sigmoidf_(accV[j]) * W3V[n];   // g2V
                sg2reg[j] = sigmoidf_(accL[j]);
                float h2 = softplusf(accL[j]);
                const float* wr = &W3L[n*21];
                #pragma unroll
                for (int k = 0; k < 21; ++k) yp[k] += h2 * wr[k];
            }
            #pragma unroll
            for (int k = 0; k < 21; ++k) atomicAdd(&Sl[FL+k], yp[k]);
        }
        __syncthreads();

        // ---------------- P2: V backward (own n-slice): g1V -> gtV ----------------
        {
            float g1v[SLC];
            #pragma unroll
            for (int j = 0; j < SLC; ++j) g1v[j] = 0.0f;
            for (int nn = 0; nn < 128; nn += 8) {
                float gr[8];
                #pragma unroll
                for (int t = 0; t < 8; ++t) gr[t] = HrowG[nn+t];
                #pragma unroll
                for (int j = 0; j < SLC; ++j) {
                    const float4* w4 = (const float4*)&W2V[(c0+j)*128 + nn];
                    float4 a = w4[0], b = w4[1];
                    g1v[j] += gr[0]*a.x + gr[1]*a.y + gr[2]*a.z + gr[3]*a.w
                            + gr[4]*b.x + gr[5]*b.y + gr[6]*b.z + gr[7]*b.w;
                }
            }
            float gtv[12];
            #pragma unroll
            for (int d = 0; d < 12; ++d) gtv[d] = 0.0f;
            #pragma unroll
            for (int j = 0; j < SLC; ++j) {
                float g1h = g1v[j] * (1.0f - __expf(-HrowV[c0+j]));   // sigmoid(z1V)
                const float4* w4 = (const float4*)&W1VT[(c0+j)*12];
                float4 wa = w4[0], wb = w4[1], wc = w4[2];
                gtv[0] += g1h*wa.x; gtv[1] += g1h*wa.y; gtv[2]  += g1h*wa.z; gtv[3]  += g1h*wa.w;
                gtv[4] += g1h*wb.x; gtv[5] += g1h*wb.y; gtv[6]  += g1h*wb.z; gtv[7]  += g1h*wb.w;
                gtv[8] += g1h*wc.x; gtv[9] += g1h*wc.y; gtv[10] += g1h*wc.z; gtv[11] += g1h*wc.w;
            }
            #pragma unroll
            for (int d = 0; d < 12; ++d) atomicAdd(&Sl[FGV+d], gtv[d]);
        }
        __syncthreads();

        // ---------------- P3: dh1 (JVP layer-1) -> HV; roles: M,u,p,r / dV ----------------
        {
            float dtv[12];
            #pragma unroll
            for (int i = 0; i < 6; ++i) { dtv[2*i] = -tt[2*i+1]*qd[i]; dtv[2*i+1] = tt[2*i]*qd[i]; }
            #pragma unroll
            for (int j = 0; j < SLC; ++j) {
                int m = c0 + j;
                const float4* w4 = (const float4*)&W1LT[m*12];
                float4 wa = w4[0], wb = w4[1], wc = w4[2];
                float dz1 = dtv[0]*wa.x + dtv[1]*wa.y + dtv[2] *wa.z + dtv[3] *wa.w
                          + dtv[4]*wb.x + dtv[5]*wb.y + dtv[6] *wb.z + dtv[7] *wb.w
                          + dtv[8]*wc.x + dtv[9]*wc.y + dtv[10]*wc.z + dtv[11]*wc.w;
                float s1 = 1.0f - __expf(-Hrow1[m]);   // sigmoid(z1L) from LDS h1L
                HrowV[m] = s1 * dz1;                   // dh1 (overwrites dead h1V)
            }
            if (wv == 0 && hf == 0) {   // M = L L^T + eps I ; u = M qd ; p = L^T qd ; r = L^T u
                float Lv[21];
                #pragma unroll
                for (int t = 0; t < 21; ++t) Lv[t] = Sl[FL+t];
                #pragma unroll
                for (int i = 0; i < 6; ++i) {
                    #pragma unroll
                    for (int jj = 0; jj <= i; ++jj) {
                        float s = 0.0f;
                        #pragma unroll
                        for (int k = 0; k <= jj; ++k)
                            s += Lv[(i*(i+1))/2 + k] * Lv[(jj*(jj+1))/2 + k];
                        if (i == jj) s += EPSc;
                        Sl[FM + i*6 + jj] = s;
                        Sl[FM + jj*6 + i] = s;
                    }
                }
                float um[6];
                #pragma unroll
                for (int i = 0; i < 6; ++i) {
                    float s = 0.0f;
                    #pragma unroll
                    for (int jj = 0; jj < 6; ++jj) s += Sl[FM + i*6 + jj] * qd[jj];
                    um[i] = s; Sl[FU+i] = s;
                }
                float pv[6], rv[6];
                #pragma unroll
                for (int i = 0; i < 6; ++i) { pv[i] = 0.0f; rv[i] = 0.0f; }
                #pragma unroll
                for (int t = 0; t < 21; ++t) {
                    pv[TCW[t]] += Lv[t] * qd[TRW[t]];
                    rv[TCW[t]] += Lv[t] * um[TRW[t]];
                }
                #pragma unroll
                for (int i = 0; i < 6; ++i) { Sl[FP+i] = pv[i]; Sl[FR+i] = rv[i]; }
            } else if (wv == 1 && hf == 0) {
                #pragma unroll
                for (int i = 0; i < 6; ++i)
                    Sl[FDV+i] = -tt[2*i+1]*Sl[FGV+2*i] + tt[2*i]*Sl[FGV+2*i+1];
            }
        }
        __syncthreads();

        // ---------------- P4: dz2 (JVP layer-2) -> dy atomic; gh2 -> gz2 into G ----------------
        {
            float dz2[SLC];
            #pragma unroll
            for (int j = 0; j < SLC; ++j) dz2[j] = 0.0f;
            for (int m8 = 0; m8 < 128; m8 += 8) {
                float dr[8];
                #pragma unroll
                for (int t = 0; t < 8; ++t) dr[t] = HrowV[m8+t];
                #pragma unroll
                for (int t = 0; t < 8; ++t) {
                    const float4* w4 = (const float4*)&W2L[(m8+t)*128 + c0];
                    float4 wa = w4[0], wb = w4[1];
                    dz2[0] += dr[t]*wa.x; dz2[1] += dr[t]*wa.y;
                    dz2[2] += dr[t]*wa.z; dz2[3] += dr[t]*wa.w;
                    dz2[4] += dr[t]*wb.x; dz2[5] += dr[t]*wb.y;
                    dz2[6] += dr[t]*wb.z; dz2[7] += dr[t]*wb.w;
                }
            }
            float dyp[21];
            #pragma unroll
            for (int k = 0; k < 21; ++k) dyp[k] = 0.0f;
            #pragma unroll
            for (int j = 0; j < SLC; ++j) {
                float dh2 = sg2reg[j] * dz2[j];
                const float* wr = &W3L[(c0+j)*21];
                #pragma unroll
                for (int k = 0; k < 21; ++k) dyp[k] += dh2 * wr[k];
            }
            #pragma unroll
            for (int k = 0; k < 21; ++k) atomicAdd(&Sl[FDY+k], dyp[k]);
            // VJP seed: gy[t] = u[R]p[C] + qd[R]r[C]; gh2 = W3L gy; gz2 -> G
            float gy[21];
            {
                float uu[6], pp[6], rr[6];
                #pragma unroll
                for (int i = 0; i < 6; ++i) { uu[i]=Sl[FU+i]; pp[i]=Sl[FP+i]; rr[i]=Sl[FR+i]; }
                #pragma unroll
                for (int t = 0; t < 21; ++t)
                    gy[t] = uu[TRW[t]]*pp[TCW[t]] + qd[TRW[t]]*rr[TCW[t]];
            }
            #pragma unroll
            for (int j = 0; j < SLC; ++j) {
                const float* wr = &W3L[(c0+j)*21];
                float gh2 = 0.0f;
                #pragma unroll
                for (int k = 0; k < 21; ++k) gh2 += wr[k] * gy[k];
                HrowG[c0+j] = sg2reg[j] * gh2;         // gz2 (overwrites dead g2V)
            }
        }
        __syncthreads();

        // ---------------- P5: VJP layer-1 -> gtL atomic; role: B, c1 ----------------
        {
            float gh1[SLC];
            #pragma unroll
            for (int j = 0; j < SLC; ++j) gh1[j] = 0.0f;
            for (int nn = 0; nn < 128; nn += 8) {
                float gr[8];
                #pragma unroll
                for (int t = 0; t < 8; ++t) gr[t] = HrowG[nn+t];
                #pragma unroll
                for (int j = 0; j < SLC; ++j) {
                    const float4* w4 = (const float4*)&W2L[(c0+j)*128 + nn];
                    float4 a = w4[0], b = w4[1];
                    gh1[j] += gr[0]*a.x + gr[1]*a.y + gr[2]*a.z + gr[3]*a.w
                            + gr[4]*b.x + gr[5]*b.y + gr[6]*b.z + gr[7]*b.w;
                }
            }
            float gtl[12];
            #pragma unroll
            for (int d = 0; d < 12; ++d) gtl[d] = 0.0f;
            #pragma unroll
            for (int j = 0; j < SLC; ++j) {
                float gz1 = (1.0f - __expf(-Hrow1[c0+j])) * gh1[j];   // sigmoid(z1L)*gh1
                const float4* w4 = (const float4*)&W1LT[(c0+j)*12];
                float4 wa = w4[0], wb = w4[1], wc = w4[2];
                gtl[0] += gz1*wa.x; gtl[1] += gz1*wa.y; gtl[2]  += gz1*wa.z; gtl[3]  += gz1*wa.w;
                gtl[4] += gz1*wb.x; gtl[5] += gz1*wb.y; gtl[6]  += gz1*wb.z; gtl[7]  += gz1*wb.w;
                gtl[8] += gz1*wc.x; gtl[9] += gz1*wc.y; gtl[10] += gz1*wc.z; gtl[11] += gz1*wc.w;
            }
            #pragma unroll
            for (int d = 0; d < 12; ++d) atomicAdd(&Sl[FGL+d], gtl[d]);
            if (wv == 1 && hf == 0) {   // B = dL L^T + L dL^T (lower tri); c1 = B u + M B qd
                float Lv[21], dLv[21];
                #pragma unroll
                for (int t = 0; t < 21; ++t) { Lv[t] = Sl[FL+t]; dLv[t] = Sl[FDY+t]; }
                float Bl[21];   // lower triangle of symmetric B
                #pragma unroll
                for (int i = 0; i < 6; ++i) {
                    #pragma unroll
                    for (int jj = 0; jj <= i; ++jj) {
                        float s = 0.0f;
                        #pragma unroll
                        for (int k = 0; k <= jj; ++k)
                            s += dLv[(i*(i+1))/2+k]*Lv[(jj*(jj+1))/2+k]
                               + Lv[(i*(i+1))/2+k]*dLv[(jj*(jj+1))/2+k];
                        Bl[(i*(i+1))/2 + jj] = s;
                    }
                }
                float uu[6];
                #pragma unroll
                for (int i = 0; i < 6; ++i) uu[i] = Sl[FU+i];
                float Bq[6], Bu[6];
                #pragma unroll
                for (int i = 0; i < 6; ++i) {
                    float s1 = 0.0f, s2 = 0.0f;
                    #pragma unroll
                    for (int jj = 0; jj < 6; ++jj) {
                        float Bij = (jj <= i) ? Bl[(i*(i+1))/2 + jj] : Bl[(jj*(jj+1))/2 + i];
                        s1 += Bij*qd[jj]; s2 += Bij*uu[jj];
                    }
                    Bq[i] = s1; Bu[i] = s2;
                }
                #pragma unroll
                for (int i = 0; i < 6; ++i) {
                    float s = 0.0f;
                    #pragma unroll
                    for (int jj = 0; jj < 6; ++jj) s += Sl[FM+i*6+jj]*Bq[jj];
                    Sl[FC1+i] = Bu[i] + s;
                }
            }
        }
        __syncthreads();

        // ---------------- P6: epilogue (wave 0, half 0): c, rhs, inv(tril(M)), qddot, RK ------
        if (wv == 0 && hf == 0) {
            float rhs[6];
            #pragma unroll
            for (int i = 0; i < 6; ++i) {
                float c2i = 2.0f*(-tt[2*i+1]*Sl[FGL+2*i] + tt[2*i]*Sl[FGL+2*i+1]);
                float c = Sl[FC1+i] - 0.5f*c2i;
                rhs[i] = aIn[gs*6+i] - c - Sl[FDV+i];
            }
            float Li[21];
            #pragma unroll
            for (int j = 0; j < 6; ++j) {
                float x[6];
                x[j] = 1.0f / Sl[FM + j*6 + j];
                #pragma unroll
                for (int i2 = j+1; i2 < 6; ++i2) {
                    float s = 0.0f;
                    #pragma unroll
                    for (int k = j; k < i2; ++k) s += Sl[FM + i2*6 + k]*x[k];
                    x[i2] = -s / Sl[FM + i2*6 + i2];
                }
                #pragma unroll
                for (int i2 = j; i2 < 6; ++i2) Li[(i2*(i2+1))/2 + j] = x[i2];
            }
            float y1[6];
            #pragma unroll
            for (int i = 0; i < 6; ++i) {
                float s = 0.0f;
                #pragma unroll
                for (int j = 0; j <= i; ++j) s += Li[(i*(i+1))/2+j]*rhs[j];
                y1[i] = s;
            }
            float qdd2[6];
            #pragma unroll
            for (int i = 0; i < 6; ++i) {
                float s = 0.0f;
                #pragma unroll
                for (int k = i; k < 6; ++k) s += Li[(k*(k+1))/2+i]*y1[k];
                qdd2[i] = s;
            }
            if (stage == 0) {
                #pragma unroll
                for (int i = 0; i < 6; ++i) {
                    Sl[FKQ+i] = qdd2[i];
                    Sl[FQ+i]  = Sl[FQ+i] + ADc*qd[i];
                    Sl[FQD+i] = qd[i] + ADc*qdd2[i];
                }
            } else {
                #pragma unroll
                for (int i = 0; i < 6; ++i) {
                    float q0 = o[gs*18+i], qd0 = o[gs*18+6+i];
                    out[gs*18+i]    = q0  + DTc*(0.25f*qd0 + 0.75f*qd[i]);
                    out[gs*18+6+i]  = qd0 + DTc*(0.25f*Sl[FKQ+i] + 0.75f*qdd2[i]);
                    out[gs*18+12+i] = o[gs*18+12+i];
                }
            }
        }
        __syncthreads();
    }
}

extern "C" void kernel_launch(void* const* d_in, const int* in_sizes, int n_in,
                              void* d_out, int out_size, void* d_ws, size_t ws_size,
                              hipStream_t stream) {
    const float* o   = (const float*)d_in[0];
    const float* a   = (const float*)d_in[1];
    const float* W1L = (const float*)d_in[2];
    const float* b1L = (const float*)d_in[3];
    const float* W2L = (const float*)d_in[4];
    const float* b2L = (const float*)d_in[5];
    const float* W3L = (const float*)d_in[6];
    const float* b3L = (const float*)d_in[7];
    const float* W1V = (const float*)d_in[8];
    const float* b1V = (const float*)d_in[9];
    const float* W2V = (const float*)d_in[10];
    const float* b2V = (const float*)d_in[11];
    const float* W3V = (const float*)d_in[12];
    float* ws   = (float*)d_ws;
    float* outp = (float*)d_out;

    hipLaunchKernelGGL(prep_kernel, dim3(12), dim3(256), 0, stream, W1L, W1V, ws);
    hipLaunchKernelGGL(lnn_kernel, dim3(32768/SMP), dim3(NT), 0, stream,
        o, a, b1L, W2L, b2L, W3L, b3L, b1V, W2V, b2V, W3V,
        ws, ws + 1536, outp);
}

// Round 8
// 584.401 us; speedup vs baseline: 6.6763x; 6.6763x over previous
//
#include <hip/hip_runtime.h>

#define SMP 64      // samples per block (= lanes per wave)
#define NW 8        // waves per block (512 threads)
#define NT (NW*64)
#define SLC 16      // hidden columns per wave slice (128/NW)

constexpr float DTc  = 0.02f;
constexpr float ADc  = (2.0f/3.0f)*0.02f;   // alpha*DT
constexpr float EPSc = 1e-6f;

// S (per-sample small state) field offsets, stride 151 (odd -> conflict-free)
#define FQ   0    // q (6)
#define FQD  6    // qdot (6)
#define FL   12   // 21 tril entries of L (y accumulator, init = b3L)
#define FM   33   // 36 full symmetric M
#define FU   69   // u = M qd (6)
#define FP   75   // p = L^T qd (6)
#define FR   81   // r = L^T u (6)
#define FDY  87   // dy: JVP of y along qd (21, atomic)
#define FDV  108  // dV/dq (6)
#define FGV  114  // V-grad wrt trig feats (12, atomic)
#define FGL  126  // c2-scalar grad wrt trig feats (12, atomic)
#define FC1  138  // c1 = B u + M B qd (6)
#define FKQ  144  // qddot of stage 1 (k1) (6)
#define SSTR 151

#define HS 129    // odd stride for 128-vectors

// Discipline learned over rounds 0-7: the ONLY no-spill build (round 0,
// 116 VGPR, WRITE_SIZE = pure output) had ZERO register arrays live across
// any __syncthreads(). Every spilling variant carried a 8-16 float array
// across 3 barriers (27 MB..2.7 GB scratch traffic). This version re-phases
// the JVP+VJP algorithm so ALL cross-phase state lives in LDS:
//   HV: h1V (P0-P2) -> dh1 (P2-P3);  G: g2V (P1-P2) -> sg2 (P3-P5a) -> gz2 (P5a-P5b)

__device__ __forceinline__ float softplusf(float z) {
    return fmaxf(z, 0.0f) + __logf(1.0f + __expf(-fabsf(z)));
}
__device__ __forceinline__ float sigmoidf_(float z) {
    float t = __expf(-fabsf(z));
    float r = 1.0f / (1.0f + t);
    return z >= 0.0f ? r : t * r;
}

__global__ void prep_kernel(const float* __restrict__ W1L, const float* __restrict__ W1V,
                            float* __restrict__ ws) {
    int idx = blockIdx.x*256 + threadIdx.x;
    if (idx < 1536) {                       // W1LT[n*12+d] = W1L[d*128+n]
        int n = idx / 12, d = idx % 12;
        ws[idx] = W1L[d*128 + n];
    } else if (idx < 3072) {                // W1VT[m*12+d] = W1V[d*128+m]
        int j = idx - 1536;
        int m = j / 12, d = j % 12;
        ws[idx] = W1V[d*128 + m];
    }
}

__launch_bounds__(NT, 2)
__global__ void lnn_kernel(
    const float* __restrict__ o,   const float* __restrict__ aIn,
    const float* __restrict__ b1L, const float* __restrict__ W2L,
    const float* __restrict__ b2L, const float* __restrict__ W3L,
    const float* __restrict__ b3L,
    const float* __restrict__ b1V, const float* __restrict__ W2V,
    const float* __restrict__ b2V, const float* __restrict__ W3V,
    const float* __restrict__ W1LT, const float* __restrict__ W1VT,
    float* __restrict__ out)
{
    __shared__ float H1[SMP*HS];    // h1L = softplus(z1L), whole stage
    __shared__ float HVs[SMP*HS];   // h1V (P0-P2), then dh1 (P2-P3)
    __shared__ float G[SMP*HS];     // g2V (P1-P2), sg2 (P3-P5a), gz2 (P5a-P5b)
    __shared__ float S[SMP*SSTR];

    const int tid  = threadIdx.x;
    const int lane = tid & 63;
    const int wv   = __builtin_amdgcn_readfirstlane(tid >> 6);
    const int gs   = blockIdx.x * SMP + lane;     // global sample of this lane
    const int n0   = __builtin_amdgcn_readfirstlane(wv * SLC);
    float* Sl    = &S[lane*SSTR];
    float* Hrow1 = &H1[lane*HS];
    float* HrowV = &HVs[lane*HS];
    float* HrowG = &G[lane*HS];

    constexpr int TRW[21] = {0,1,1,2,2,2,3,3,3,3,4,4,4,4,4,5,5,5,5,5,5};
    constexpr int TCW[21] = {0,0,1,0,1,2,0,1,2,3,0,1,2,3,4,0,1,2,3,4,5};

    float qd[6], tt[12];

    for (int stage = 0; stage < 2; ++stage) {
        // ---------------- P0: state load + trig + layer-1 (both nets, own slice) ----------------
        {
            float qv[6];
            if (stage == 0) {
                #pragma unroll
                for (int i = 0; i < 6; ++i) { qv[i] = o[gs*18+i]; qd[i] = o[gs*18+6+i]; }
                if (wv == 0) {
                    #pragma unroll
                    for (int i = 0; i < 6; ++i) { Sl[FQ+i] = qv[i]; Sl[FQD+i] = qd[i]; }
                }
            } else {
                #pragma unroll
                for (int i = 0; i < 6; ++i) { qv[i] = Sl[FQ+i]; qd[i] = Sl[FQD+i]; }
            }
            #pragma unroll
            for (int i = 0; i < 6; ++i) { tt[2*i] = cosf(qv[i]); tt[2*i+1] = sinf(qv[i]); }
        }
        if (wv == 1) {
            #pragma unroll
            for (int k = 0; k < 21; ++k) Sl[FL+k] = b3L[k];
        } else if (wv == 2) {
            #pragma unroll
            for (int k = 0; k < 21; ++k) Sl[FDY+k] = 0.0f;
        } else if (wv == 3) {
            #pragma unroll
            for (int d = 0; d < 12; ++d) { Sl[FGV+d] = 0.0f; Sl[FGL+d] = 0.0f; }
        }
        #pragma unroll
        for (int j = 0; j < SLC; ++j) {
            int m = n0 + j;
            const float4* wL = (const float4*)&W1LT[m*12];
            float4 la = wL[0], lb = wL[1], lc = wL[2];
            float zL = b1L[m]
                + tt[0]*la.x + tt[1]*la.y + tt[2] *la.z + tt[3] *la.w
                + tt[4]*lb.x + tt[5]*lb.y + tt[6] *lb.z + tt[7] *lb.w
                + tt[8]*lc.x + tt[9]*lc.y + tt[10]*lc.z + tt[11]*lc.w;
            Hrow1[m] = softplusf(zL);
            const float4* wV = (const float4*)&W1VT[m*12];
            float4 va = wV[0], vb = wV[1], vc = wV[2];
            float zV = b1V[m]
                + tt[0]*va.x + tt[1]*va.y + tt[2] *va.z + tt[3] *va.w
                + tt[4]*vb.x + tt[5]*vb.y + tt[6] *vb.z + tt[7] *vb.w
                + tt[8]*vc.x + tt[9]*vc.y + tt[10]*vc.z + tt[11]*vc.w;
            HrowV[m] = softplusf(zV);
        }
        __syncthreads();

        // ---------------- P1: V layer-2 -> g2V into G ----------------
        {
            float accV[SLC];
            #pragma unroll
            for (int j = 0; j < SLC; ++j) accV[j] = b2V[n0+j];
            for (int m8 = 0; m8 < 128; m8 += 8) {
                float hvr[8];
                #pragma unroll
                for (int t = 0; t < 8; ++t) hvr[t] = HrowV[m8+t];
                #pragma unroll
                for (int t = 0; t < 8; ++t) {
                    const float4* v4 = (const float4*)&W2V[(m8+t)*128 + n0];
                    #pragma unroll
                    for (int g = 0; g < 4; ++g) {
                        float4 v = v4[g];
                        accV[4*g+0] += hvr[t]*v.x; accV[4*g+1] += hvr[t]*v.y;
                        accV[4*g+2] += hvr[t]*v.z; accV[4*g+3] += hvr[t]*v.w;
                    }
                }
            }
            #pragma unroll
            for (int j = 0; j < SLC; ++j) {
                int n = n0 + j;
                HrowG[n] = sigmoidf_(accV[j]) * W3V[n];   // g2V
            }
        }
        __syncthreads();

        // ---------------- P2: V backward -> gtV atomic; then dh1 -> HV (own slice) ------------
        {
            float g1v[SLC];
            #pragma unroll
            for (int j = 0; j < SLC; ++j) g1v[j] = 0.0f;
            for (int nn = 0; nn < 128; nn += 8) {
                float gr[8];
                #pragma unroll
                for (int t = 0; t < 8; ++t) gr[t] = HrowG[nn+t];
                #pragma unroll
                for (int j = 0; j < SLC; ++j) {
                    const float4* w4 = (const float4*)&W2V[(n0+j)*128 + nn];
                    float4 a = w4[0], b = w4[1];
                    g1v[j] += gr[0]*a.x + gr[1]*a.y + gr[2]*a.z + gr[3]*a.w
                            + gr[4]*b.x + gr[5]*b.y + gr[6]*b.z + gr[7]*b.w;
                }
            }
            float gtv[12];
            #pragma unroll
            for (int d = 0; d < 12; ++d) gtv[d] = 0.0f;
            #pragma unroll
            for (int j = 0; j < SLC; ++j) {
                float g1h = g1v[j] * (1.0f - __expf(-HrowV[n0+j]));   // sigmoid(z1V)
                const float4* w4 = (const float4*)&W1VT[(n0+j)*12];
                float4 wa = w4[0], wb = w4[1], wc = w4[2];
                gtv[0] += g1h*wa.x; gtv[1] += g1h*wa.y; gtv[2]  += g1h*wa.z; gtv[3]  += g1h*wa.w;
                gtv[4] += g1h*wb.x; gtv[5] += g1h*wb.y; gtv[6]  += g1h*wb.z; gtv[7]  += g1h*wb.w;
                gtv[8] += g1h*wc.x; gtv[9] += g1h*wc.y; gtv[10] += g1h*wc.z; gtv[11] += g1h*wc.w;
            }
            #pragma unroll
            for (int d = 0; d < 12; ++d) atomicAdd(&Sl[FGV+d], gtv[d]);
            // dh1 = sigmoid(z1L) * dz1 into HV own slice (h1V own slice already consumed)
            float dtv[12];
            #pragma unroll
            for (int i = 0; i < 6; ++i) { dtv[2*i] = -tt[2*i+1]*qd[i]; dtv[2*i+1] = tt[2*i]*qd[i]; }
            #pragma unroll
            for (int j = 0; j < SLC; ++j) {
                int m = n0 + j;
                const float4* w4 = (const float4*)&W1LT[m*12];
                float4 wa = w4[0], wb = w4[1], wc = w4[2];
                float dz1 = dtv[0]*wa.x + dtv[1]*wa.y + dtv[2] *wa.z + dtv[3] *wa.w
                          + dtv[4]*wb.x + dtv[5]*wb.y + dtv[6] *wb.z + dtv[7] *wb.w
                          + dtv[8]*wc.x + dtv[9]*wc.y + dtv[10]*wc.z + dtv[11]*wc.w;
                float s1 = 1.0f - __expf(-Hrow1[m]);   // sigmoid(z1L) from h1L
                HrowV[m] = s1 * dz1;
            }
        }
        __syncthreads();

        // -------- P3: L layer-2 + JVP in ONE W2L pass; y->FL, dy->FDY atomics; sg2 -> G -------
        {
            float accL[SLC], dz2[SLC];
            #pragma unroll
            for (int j = 0; j < SLC; ++j) { accL[j] = b2L[n0+j]; dz2[j] = 0.0f; }
            for (int m8 = 0; m8 < 128; m8 += 8) {
                float h1r[8], dr[8];
                #pragma unroll
                for (int t = 0; t < 8; ++t) { h1r[t] = Hrow1[m8+t]; dr[t] = HrowV[m8+t]; }
                #pragma unroll
                for (int t = 0; t < 8; ++t) {
                    const float4* w4 = (const float4*)&W2L[(m8+t)*128 + n0];
                    #pragma unroll
                    for (int g = 0; g < 4; ++g) {
                        float4 w = w4[g];          // one weight read feeds BOTH accumulations
                        accL[4*g+0] += h1r[t]*w.x; accL[4*g+1] += h1r[t]*w.y;
                        accL[4*g+2] += h1r[t]*w.z; accL[4*g+3] += h1r[t]*w.w;
                        dz2[4*g+0]  += dr[t]*w.x;  dz2[4*g+1]  += dr[t]*w.y;
                        dz2[4*g+2]  += dr[t]*w.z;  dz2[4*g+3]  += dr[t]*w.w;
                    }
                }
            }
            float yp[21];
            #pragma unroll
            for (int k = 0; k < 21; ++k) yp[k] = 0.0f;
            #pragma unroll
            for (int j = 0; j < SLC; ++j) {
                float h2 = softplusf(accL[j]);
                const float* wr = &W3L[(n0+j)*21];
                #pragma unroll
                for (int k = 0; k < 21; ++k) yp[k] += h2 * wr[k];
            }
            #pragma unroll
            for (int k = 0; k < 21; ++k) atomicAdd(&Sl[FL+k], yp[k]);
            float dyp[21];
            #pragma unroll
            for (int k = 0; k < 21; ++k) dyp[k] = 0.0f;
            #pragma unroll
            for (int j = 0; j < SLC; ++j) {
                float sg2 = sigmoidf_(accL[j]);
                float dh2 = sg2 * dz2[j];
                const float* wr = &W3L[(n0+j)*21];
                #pragma unroll
                for (int k = 0; k < 21; ++k) dyp[k] += dh2 * wr[k];
                HrowG[n0+j] = sg2;                 // park sg2 in G (g2V is dead)
            }
            #pragma unroll
            for (int k = 0; k < 21; ++k) atomicAdd(&Sl[FDY+k], dyp[k]);
        }
        __syncthreads();

        // ---------------- P4: roles: M,u,p,r (wv0) / dV (wv1) ----------------
        if (wv == 0) {
            float Lv[21];
            #pragma unroll
            for (int t = 0; t < 21; ++t) Lv[t] = Sl[FL+t];
            #pragma unroll
            for (int i = 0; i < 6; ++i) {
                #pragma unroll
                for (int jj = 0; jj <= i; ++jj) {
                    float s = 0.0f;
                    #pragma unroll
                    for (int k = 0; k <= jj; ++k)
                        s += Lv[(i*(i+1))/2 + k] * Lv[(jj*(jj+1))/2 + k];
                    if (i == jj) s += EPSc;
                    Sl[FM + i*6 + jj] = s;
                    Sl[FM + jj*6 + i] = s;
                }
            }
            float um[6];
            #pragma unroll
            for (int i = 0; i < 6; ++i) {
                float s = 0.0f;
                #pragma unroll
                for (int jj = 0; jj < 6; ++jj) s += Sl[FM + i*6 + jj] * qd[jj];
                um[i] = s; Sl[FU+i] = s;
            }
            float pv[6], rv[6];
            #pragma unroll
            for (int i = 0; i < 6; ++i) { pv[i] = 0.0f; rv[i] = 0.0f; }
            #pragma unroll
            for (int t = 0; t < 21; ++t) {
                pv[TCW[t]] += Lv[t] * qd[TRW[t]];
                rv[TCW[t]] += Lv[t] * um[TRW[t]];
            }
            #pragma unroll
            for (int i = 0; i < 6; ++i) { Sl[FP+i] = pv[i]; Sl[FR+i] = rv[i]; }
        } else if (wv == 1) {
            #pragma unroll
            for (int i = 0; i < 6; ++i)
                Sl[FDV+i] = -tt[2*i+1]*Sl[FGV+2*i] + tt[2*i]*Sl[FGV+2*i+1];
        }
        __syncthreads();

        // ---------------- P5a: gy; gh2 own slice; G: sg2 -> gz2 (in place) ----------------
        {
            float gy[21];
            {
                float uu[6], pp[6], rr[6];
                #pragma unroll
                for (int i = 0; i < 6; ++i) { uu[i]=Sl[FU+i]; pp[i]=Sl[FP+i]; rr[i]=Sl[FR+i]; }
                #pragma unroll
                for (int t = 0; t < 21; ++t)
                    gy[t] = uu[TRW[t]]*pp[TCW[t]] + qd[TRW[t]]*rr[TCW[t]];
            }
            #pragma unroll
            for (int j = 0; j < SLC; ++j) {
                const float* wr = &W3L[(n0+j)*21];
                float gh2 = 0.0f;
                #pragma unroll
                for (int k = 0; k < 21; ++k) gh2 += wr[k] * gy[k];
                HrowG[n0+j] = HrowG[n0+j] * gh2;       // gz2 = sg2 * gh2 (own slice)
            }
        }
        __syncthreads();

        // ---------------- P5b: VJP layer-1 -> gtL atomic; role: B, c1 (wv1) ----------------
        {
            float gh1[SLC];
            #pragma unroll
            for (int j = 0; j < SLC; ++j) gh1[j] = 0.0f;
            for (int nn = 0; nn < 128; nn += 8) {
                float gr[8];
                #pragma unroll
                for (int t = 0; t < 8; ++t) gr[t] = HrowG[nn+t];
                #pragma unroll
                for (int j = 0; j < SLC; ++j) {
                    const float4* w4 = (const float4*)&W2L[(n0+j)*128 + nn];
                    float4 a = w4[0], b = w4[1];
                    gh1[j] += gr[0]*a.x + gr[1]*a.y + gr[2]*a.z + gr[3]*a.w
                            + gr[4]*b.x + gr[5]*b.y + gr[6]*b.z + gr[7]*b.w;
                }
            }
            float gtl[12];
            #pragma unroll
            for (int d = 0; d < 12; ++d) gtl[d] = 0.0f;
            #pragma unroll
            for (int j = 0; j < SLC; ++j) {
                float gz1 = (1.0f - __expf(-Hrow1[n0+j])) * gh1[j];   // sigmoid(z1L)*gh1
                const float4* w4 = (const float4*)&W1LT[(n0+j)*12];
                float4 wa = w4[0], wb = w4[1], wc = w4[2];
                gtl[0] += gz1*wa.x; gtl[1] += gz1*wa.y; gtl[2]  += gz1*wa.z; gtl[3]  += gz1*wa.w;
                gtl[4] += gz1*wb.x; gtl[5] += gz1*wb.y; gtl[6]  += gz1*wb.z; gtl[7]  += gz1*wb.w;
                gtl[8] += gz1*wc.x; gtl[9] += gz1*wc.y; gtl[10] += gz1*wc.z; gtl[11] += gz1*wc.w;
            }
            #pragma unroll
            for (int d = 0; d < 12; ++d) atomicAdd(&Sl[FGL+d], gtl[d]);
            if (wv == 1) {   // B = dL L^T + L dL^T (lower tri); c1 = B u + M B qd
                float Lv[21], dLv[21];
                #pragma unroll
                for (int t = 0; t < 21; ++t) { Lv[t] = Sl[FL+t]; dLv[t] = Sl[FDY+t]; }
                float Bl[21];
                #pragma unroll
                for (int i = 0; i < 6; ++i) {
                    #pragma unroll
                    for (int jj = 0; jj <= i; ++jj) {
                        float s = 0.0f;
                        #pragma unroll
                        for (int k = 0; k <= jj; ++k)
                            s += dLv[(i*(i+1))/2+k]*Lv[(jj*(jj+1))/2+k]
                               + Lv[(i*(i+1))/2+k]*dLv[(jj*(jj+1))/2+k];
                        Bl[(i*(i+1))/2 + jj] = s;
                    }
                }
                float uu[6];
                #pragma unroll
                for (int i = 0; i < 6; ++i) uu[i] = Sl[FU+i];
                float Bq[6], Bu[6];
                #pragma unroll
                for (int i = 0; i < 6; ++i) {
                    float s1 = 0.0f, s2 = 0.0f;
                    #pragma unroll
                    for (int jj = 0; jj < 6; ++jj) {
                        float Bij = (jj <= i) ? Bl[(i*(i+1))/2 + jj] : Bl[(jj*(jj+1))/2 + i];
                        s1 += Bij*qd[jj]; s2 += Bij*uu[jj];
                    }
                    Bq[i] = s1; Bu[i] = s2;
                }
                #pragma unroll
                for (int i = 0; i < 6; ++i) {
                    float s = 0.0f;
                    #pragma unroll
                    for (int jj = 0; jj < 6; ++jj) s += Sl[FM+i*6+jj]*Bq[jj];
                    Sl[FC1+i] = Bu[i] + s;
                }
            }
        }
        __syncthreads();

        // ---------------- P6: epilogue (wave 0): c, rhs, inv(tril(M)), qddot, RK update --------
        if (wv == 0) {
            float rhs[6];
            #pragma unroll
            for (int i = 0; i < 6; ++i) {
                float c2i = 2.0f*(-tt[2*i+1]*Sl[FGL+2*i] + tt[2*i]*Sl[FGL+2*i+1]);
                float c = Sl[FC1+i] - 0.5f*c2i;
                rhs[i] = aIn[gs*6+i] - c - Sl[FDV+i];
            }
            float Li[21];
            #pragma unroll
            for (int j = 0; j < 6; ++j) {
                float x[6];
                x[j] = 1.0f / Sl[FM + j*6 + j];
                #pragma unroll
                for (int i2 = j+1; i2 < 6; ++i2) {
                    float s = 0.0f;
                    #pragma unroll
                    for (int k = j; k < i2; ++k) s += Sl[FM + i2*6 + k]*x[k];
                    x[i2] = -s / Sl[FM + i2*6 + i2];
                }
                #pragma unroll
                for (int i2 = j; i2 < 6; ++i2) Li[(i2*(i2+1))/2 + j] = x[i2];
            }
            float y1[6];
            #pragma unroll
            for (int i = 0; i < 6; ++i) {
                float s = 0.0f;
                #pragma unroll
                for (int j = 0; j <= i; ++j) s += Li[(i*(i+1))/2+j]*rhs[j];
                y1[i] = s;
            }
            float qdd2[6];
            #pragma unroll
            for (int i = 0; i < 6; ++i) {
                float s = 0.0f;
                #pragma unroll
                for (int k = i; k < 6; ++k) s += Li[(k*(k+1))/2+i]*y1[k];
                qdd2[i] = s;
            }
            if (stage == 0) {
                #pragma unroll
                for (int i = 0; i < 6; ++i) {
                    Sl[FKQ+i] = qdd2[i];
                    Sl[FQ+i]  = Sl[FQ+i] + ADc*qd[i];
                    Sl[FQD+i] = qd[i] + ADc*qdd2[i];
                }
            } else {
                #pragma unroll
                for (int i = 0; i < 6; ++i) {
                    float q0 = o[gs*18+i], qd0 = o[gs*18+6+i];
                    out[gs*18+i]    = q0  + DTc*(0.25f*qd0 + 0.75f*qd[i]);
                    out[gs*18+6+i]  = qd0 + DTc*(0.25f*Sl[FKQ+i] + 0.75f*qdd2[i]);
                    out[gs*18+12+i] = o[gs*18+12+i];
                }
            }
        }
        __syncthreads();
    }
}

extern "C" void kernel_launch(void* const* d_in, const int* in_sizes, int n_in,
                              void* d_out, int out_size, void* d_ws, size_t ws_size,
                              hipStream_t stream) {
    const float* o   = (const float*)d_in[0];
    const float* a   = (const float*)d_in[1];
    const float* W1L = (const float*)d_in[2];
    const float* b1L = (const float*)d_in[3];
    const float* W2L = (const float*)d_in[4];
    const float* b2L = (const float*)d_in[5];
    const float* W3L = (const float*)d_in[6];
    const float* b3L = (const float*)d_in[7];
    const float* W1V = (const float*)d_in[8];
    const float* b1V = (const float*)d_in[9];
    const float* W2V = (const float*)d_in[10];
    const float* b2V = (const float*)d_in[11];
    const float* W3V = (const float*)d_in[12];
    float* ws   = (float*)d_ws;
    float* outp = (float*)d_out;

    hipLaunchKernelGGL(prep_kernel, dim3(12), dim3(256), 0, stream, W1L, W1V, ws);
    hipLaunchKernelGGL(lnn_kernel, dim3(32768/SMP), dim3(NT), 0, stream,
        o, a, b1L, W2L, b2L, W3L, b3L, b1V, W2V, b2V, W3V,
        ws, ws + 1536, outp);
}